// Round 1
// baseline (1243.478 us; speedup 1.0000x reference)
//
#include <hip/hip_runtime.h>
#include <math.h>

// Problem constants
#define DUP   32        // upsampled spatial dim
#define NVOX  32768     // 32^3 voxels
#define CIN   64
#define COUT  32
#define KT    27        // 3^3 taps
#define CIT   1728      // CIN*KT
#define PADX  18        // padded half-res dim (16 + 2)
#define PSP   5832      // 18^3

// Workspace layout (float offsets)
#define WS_XP   0               // [64][18][18][18] channel-first padded x
#define WS_XT   373248          // [18][18][18][64] channel-last  padded x
#define WS_OFF  746496          // [81][32768] offsets
#define WS_STAT 3400704         // [32] sum, [32] sumsq

// ---------------------------------------------------------------------------
// Prep: build zero-padded x in two layouts.
// Padded half-res index q = clamp/shift of up-space coords; q in [-1,16]
// stored at q+1 in [0,17]; pads are zero.
// ---------------------------------------------------------------------------
__global__ void prep_kernel(const float* __restrict__ x, float* __restrict__ ws) {
    int s = blockIdx.x;          // 0..5831 padded spatial cell
    int c = threadIdx.x;         // 0..63 channel
    int qw = s % 18, qh = (s / 18) % 18, qd = s / 324;
    float v = 0.f;
    if (qd >= 1 && qd <= 16 && qh >= 1 && qh <= 16 && qw >= 1 && qw <= 16)
        v = x[((c * 16 + (qd - 1)) * 16 + (qh - 1)) * 16 + (qw - 1)];
    ws[WS_XT + s * 64 + c]  = v;
    ws[WS_XP + c * PSP + s] = v;
}

// ---------------------------------------------------------------------------
// Offset conv: off[kc][p] = b_off[kc] + sum_{ci,t} w_off[kc][ci][t] * xup(ci, p+tap_t)
// One thread per voxel, 9 kc channels per thread (blockIdx.y picks group).
// Weights are wave-uniform -> scalar loads; x from channel-first padded copy.
// ---------------------------------------------------------------------------
__global__ __launch_bounds__(256) void off_conv_kernel(
        const float* __restrict__ w_off, const float* __restrict__ b_off,
        float* __restrict__ ws) {
    const float* xp = ws + WS_XP;
    float* off = ws + WS_OFF;
    int p = blockIdx.x * 256 + threadIdx.x;
    int d = p >> 10, h = (p >> 5) & 31, w = p & 31;
    int kc0 = blockIdx.y * 9;

    // Precompute 27 padded spatial indices (no bounds checks needed:
    // up-coords in [-1,32] -> q in [-1,16] -> padded row in [0,17]).
    int sp[27];
#pragma unroll
    for (int kd = 0; kd < 3; kd++)
#pragma unroll
        for (int kh = 0; kh < 3; kh++)
#pragma unroll
            for (int kw = 0; kw < 3; kw++) {
                int rd = ((d + kd - 1) >> 1) + 1;
                int rh = ((h + kh - 1) >> 1) + 1;
                int rw = ((w + kw - 1) >> 1) + 1;
                sp[(kd * 3 + kh) * 3 + kw] = (rd * 18 + rh) * 18 + rw;
            }

    float acc[9];
#pragma unroll
    for (int j = 0; j < 9; j++) acc[j] = b_off[kc0 + j];

    for (int ci = 0; ci < CIN; ci++) {
        const float* xb = xp + ci * PSP;
        const float* wb = w_off + kc0 * CIT + ci * 27;
#pragma unroll
        for (int t = 0; t < 27; t++) {
            float xv = xb[sp[t]];
#pragma unroll
            for (int j = 0; j < 9; j++)
                acc[j] += wb[j * CIT + t] * xv;
        }
    }
#pragma unroll
    for (int j = 0; j < 9; j++)
        off[(kc0 + j) * NVOX + p] = acc[j];
}

// ---------------------------------------------------------------------------
// Deformable sample + einsum + BN-stats.
// Block = 256 threads = 4 waves; 1 wave per voxel.
// Phase A: lane = input channel; trilinear gather from channel-last padded x
//          (coalesced 256B per corner), result staged in LDS s[c*27+k].
// Phase B: lane = (half, o); split-K dot of w[o][cit] . s[cit], float4.
// Stats:   per-block LDS reduction -> 64 global atomics.
// ---------------------------------------------------------------------------
__global__ __launch_bounds__(256) void deform_kernel(
        const float* __restrict__ wmat, const float* __restrict__ bias,
        float* ws, float* __restrict__ out) {
    __shared__ float smem[4 * CIT];
    __shared__ float rsum[COUT], rsq[COUT];

    const float* xt  = ws + WS_XT;
    const float* off = ws + WS_OFF;
    float* gstat = ws + WS_STAT;

    int tid  = threadIdx.x;
    int wave = tid >> 6;
    int lane = tid & 63;
    if (tid < COUT) { rsum[tid] = 0.f; rsq[tid] = 0.f; }

    int p = blockIdx.x * 4 + wave;
    int d = p >> 10, h = (p >> 5) & 31, w = p & 31;

    // Phase A: gather + trilinear. All coordinate math is wave-uniform.
    for (int k = 0; k < KT; k++) {
        int kd = k / 9, kh = (k / 3) % 3, kw = k % 3;
        float od = off[(k * 3 + 0) * NVOX + p];
        float oh = off[(k * 3 + 1) * NVOX + p];
        float ow = off[(k * 3 + 2) * NVOX + p];
        float pd = (float)(d + kd - 1) + od;
        float ph = (float)(h + kh - 1) + oh;
        float pw = (float)(w + kw - 1) + ow;
        float fd0 = floorf(pd), fh0 = floorf(ph), fw0 = floorf(pw);
        float fd = pd - fd0, fh = ph - fh0, fw = pw - fw0;
        int id = (int)fd0, ih = (int)fh0, iw = (int)fw0;
        float sv = 0.f;
#pragma unroll
        for (int dd = 0; dd < 2; dd++) {
            int di = id + dd;
            int cd = min(max(di, -2), 33);      // clamp; pads give exact 0
            int rd = (cd >> 1) + 1;
            float wd = dd ? fd : 1.f - fd;
#pragma unroll
            for (int hh = 0; hh < 2; hh++) {
                int hi = ih + hh;
                int ch = min(max(hi, -2), 33);
                int rh = (ch >> 1) + 1;
                float wh = hh ? fh : 1.f - fh;
#pragma unroll
                for (int ww2 = 0; ww2 < 2; ww2++) {
                    int wi = iw + ww2;
                    int cw = min(max(wi, -2), 33);
                    int rw = (cw >> 1) + 1;
                    float wwt = ww2 ? fw : 1.f - fw;
                    float val = xt[((rd * 18 + rh) * 18 + rw) * 64 + lane];
                    sv += wd * wh * wwt * val;
                }
            }
        }
        smem[wave * CIT + lane * 27 + k] = sv;
    }
    __syncthreads();

    // Phase B: out[o] = b[o] + sum_cit w[o][cit] * s[cit], split-K by 2 halves.
    int o    = lane & 31;
    int half = lane >> 5;
    const float* wrow = wmat + o * CIT + half * 864;
    const float* srow = smem + wave * CIT + half * 864;
    float acc = 0.f;
    for (int cc = 0; cc < 864; cc += 4) {
        float4 wv = *(const float4*)(wrow + cc);
        float4 sv = *(const float4*)(srow + cc);
        acc += wv.x * sv.x + wv.y * sv.y + wv.z * sv.z + wv.w * sv.w;
    }
    acc += __shfl_down(acc, 32);
    if (half == 0) {
        float v = acc + bias[o];
        out[o * NVOX + p] = v;              // pre-BN value
        atomicAdd(&rsum[o], v);
        atomicAdd(&rsq[o], v * v);
    }
    __syncthreads();
    if (tid < COUT) {
        atomicAdd(&gstat[tid], rsum[tid]);
        atomicAdd(&gstat[COUT + tid], rsq[tid]);
    }
}

// ---------------------------------------------------------------------------
// BN finalize + ReLU, in-place on d_out.
// ---------------------------------------------------------------------------
__global__ void bn_kernel(const float* __restrict__ ws,
                          const float* __restrict__ gamma,
                          const float* __restrict__ beta,
                          float* out) {
    int i = blockIdx.x * 256 + threadIdx.x;      // 0..1048575
    int o = i >> 15;                             // channel
    const float* gstat = ws + WS_STAT;
    const float inv = 1.f / 32768.f;
    float mean = gstat[o] * inv;
    float var  = gstat[COUT + o] * inv - mean * mean;
    float sc   = rsqrtf(var + 1e-5f) * gamma[o];
    float v = (out[i] - mean) * sc + beta[o];
    out[i] = fmaxf(v, 0.f);
}

// ---------------------------------------------------------------------------
extern "C" void kernel_launch(void* const* d_in, const int* in_sizes, int n_in,
                              void* d_out, int out_size, void* d_ws, size_t ws_size,
                              hipStream_t stream) {
    const float* x     = (const float*)d_in[0];
    const float* w_off = (const float*)d_in[1];
    const float* b_off = (const float*)d_in[2];
    const float* wmat  = (const float*)d_in[3];
    const float* bias  = (const float*)d_in[4];
    const float* gamma = (const float*)d_in[5];
    const float* beta  = (const float*)d_in[6];
    float* ws  = (float*)d_ws;
    float* out = (float*)d_out;

    hipMemsetAsync(ws + WS_STAT, 0, 64 * sizeof(float), stream);
    prep_kernel<<<PSP, 64, 0, stream>>>(x, ws);
    off_conv_kernel<<<dim3(128, 9), 256, 0, stream>>>(w_off, b_off, ws);
    deform_kernel<<<8192, 256, 0, stream>>>(wmat, bias, ws, out);
    bn_kernel<<<4096, 256, 0, stream>>>(ws, gamma, beta, out);
}

// Round 2
// 366.304 us; speedup vs baseline: 3.3947x; 3.3947x over previous
//
#include <hip/hip_runtime.h>
#include <math.h>

// Problem constants
#define NVOX  32768     // 32^3 up-res voxels
#define CIN   64
#define COUT  32
#define KT    27
#define CIT   1728      // CIN*KT
#define PSP   5832      // 18^3 padded half-res spatial

// Workspace layout (float offsets)
#define WS_XP   0                 // [64][5832] channel-first padded x
#define WS_XT   373248            // [5832][64] channel-last padded x
#define WS_WC   746496            // [8][81][64][8] parity-collapsed offset weights
#define WS_WT   1078272           // [432][32][4] transposed deform weights
#define WS_OFFT 1133568           // [32768][84] offsets, voxel-major (+128 pad)
#define WS_STAT 3886208           // [32] sum, [32] sumsq
#define OFFSTRIDE 84

// ---------------------------------------------------------------------------
// Prep: zero-padded x in two layouts. Padded idx q+1, q in [-1,16].
// ---------------------------------------------------------------------------
__global__ void prep_kernel(const float* __restrict__ x, float* __restrict__ ws) {
    int s = blockIdx.x;          // 0..5831
    int c = threadIdx.x;         // 0..63
    int qw = s % 18, qh = (s / 18) % 18, qd = s / 324;
    float v = 0.f;
    if (qd >= 1 && qd <= 16 && qh >= 1 && qh <= 16 && qw >= 1 && qw <= 16)
        v = x[((c * 16 + (qd - 1)) * 16 + (qh - 1)) * 16 + (qw - 1)];
    ws[WS_XT + s * 64 + c]  = v;
    ws[WS_XP + c * PSP + s] = v;
}

// ---------------------------------------------------------------------------
// Parity-collapse the 27-tap offset-conv weights to 8 taps per parity.
// Per axis: parity 0: cell0<-{w0}, cell1<-{w1,w2}; parity 1: cell0<-{w0,w1}, cell1<-{w2}.
// ---------------------------------------------------------------------------
__global__ void wc_prep_kernel(const float* __restrict__ w_off, float* __restrict__ ws) {
    int kc = blockIdx.x;         // 0..80
    int pi = blockIdx.y;         // 0..7
    int ci = threadIdx.x;        // 0..63
    int pd = (pi >> 2) & 1, ph = (pi >> 1) & 1, pw = pi & 1;
    const float* wsrc = w_off + (kc * 64 + ci) * 27;
    float w3[27];
#pragma unroll
    for (int t = 0; t < 27; t++) w3[t] = wsrc[t];
    float* dst = ws + WS_WC + ((pi * 81 + kc) * 64 + ci) * 8;
#pragma unroll
    for (int cd = 0; cd < 2; cd++) {
        int lod = (cd == 0) ? 0 : (pd == 0 ? 1 : 2);
        int hid = (cd == 0) ? (pd == 0 ? 0 : 1) : 2;
#pragma unroll
        for (int ch = 0; ch < 2; ch++) {
            int loh = (ch == 0) ? 0 : (ph == 0 ? 1 : 2);
            int hih = (ch == 0) ? (ph == 0 ? 0 : 1) : 2;
#pragma unroll
            for (int cw = 0; cw < 2; cw++) {
                int low = (cw == 0) ? 0 : (pw == 0 ? 1 : 2);
                int hiw = (cw == 0) ? (pw == 0 ? 0 : 1) : 2;
                float a = 0.f;
                for (int kd = lod; kd <= hid; kd++)
                    for (int kh = loh; kh <= hih; kh++)
                        for (int kw = low; kw <= hiw; kw++)
                            a += w3[kd * 9 + kh * 3 + kw];
                dst[cd * 4 + ch * 2 + cw] = a;
            }
        }
    }
}

// ---------------------------------------------------------------------------
// Transpose deform weights for coalesced Phase-B loads:
// wt[g][o][c] = wmat[o][g*4+c], g in [0,432), o in [0,32), c in [0,4)
// ---------------------------------------------------------------------------
__global__ void wt_prep_kernel(const float* __restrict__ wmat, float* __restrict__ ws) {
    int idx = blockIdx.x * 256 + threadIdx.x;    // 0..55295
    int g = idx >> 7, rem = idx & 127;
    int o = rem >> 2, comp = rem & 3;
    ws[WS_WT + idx] = wmat[o * CIT + g * 4 + comp];
}

// ---------------------------------------------------------------------------
// Offset conv via parity collapse: off[kc][p_up] for p_up of parity pi equals
// 2x2x2 conv of half-res x with Wc[pi]. Thread = half-voxel, 9 kc per block.y.
// Weight addresses are block-uniform -> scalar loads.
// Output written voxel-major: offt[p_up*84 + kc].
// ---------------------------------------------------------------------------
__global__ __launch_bounds__(256) void off_conv_kernel(
        const float* __restrict__ b_off, float* __restrict__ ws) {
    const float* xp = ws + WS_XP;
    const float* wc = ws + WS_WC;
    float* offt = ws + WS_OFFT;

    int tid = threadIdx.x;
    int phf = blockIdx.x * 256 + tid;            // half-res voxel 0..4095
    int qw = phf & 15, qh = (phf >> 4) & 15, qd = phf >> 8;
    int pi = blockIdx.z;
    int pd = (pi >> 2) & 1, ph = (pi >> 1) & 1, pw = pi & 1;
    int kc0 = blockIdx.y * 9;

    int base = ((qd + pd) * 18 + (qh + ph)) * 18 + (qw + pw);

    float acc[9];
#pragma unroll
    for (int j = 0; j < 9; j++) acc[j] = b_off[kc0 + j];

    for (int ci = 0; ci < CIN; ci++) {
        const float* xb = xp + ci * PSP + base;
        float xv[8];
        xv[0] = xb[0];   xv[1] = xb[1];
        xv[2] = xb[18];  xv[3] = xb[19];
        xv[4] = xb[324]; xv[5] = xb[325];
        xv[6] = xb[342]; xv[7] = xb[343];
        const float* wrow = wc + ((pi * 81 + kc0) * 64 + ci) * 8;
#pragma unroll
        for (int j = 0; j < 9; j++) {
            const float4* wp = (const float4*)(wrow + j * 512);
            float4 a = wp[0], b = wp[1];
            acc[j] += a.x * xv[0] + a.y * xv[1] + a.z * xv[2] + a.w * xv[3]
                    + b.x * xv[4] + b.y * xv[5] + b.z * xv[6] + b.w * xv[7];
        }
    }
    int d = 2 * qd + pd, h = 2 * qh + ph, w = 2 * qw + pw;
    int p = (d << 10) + (h << 5) + w;
#pragma unroll
    for (int j = 0; j < 9; j++)
        offt[p * OFFSTRIDE + kc0 + j] = acc[j];
}

// ---------------------------------------------------------------------------
// Deformable sample + einsum + BN stats.
// Block = 256 = 4 waves = 4 voxels.
// Phase A: wave=voxel, lane=channel. Offsets preloaded (2 coalesced loads) and
//          broadcast via shfl; tap loop fully unrolled -> pipelined gathers.
// Phase B: thread=(o, k-slice); wmat read once per BLOCK (transposed, coalesced
//          float4), applied to all 4 voxels from LDS (broadcast reads).
// ---------------------------------------------------------------------------
__global__ __launch_bounds__(256) void deform_kernel(
        const float* __restrict__ bias, float* ws, float* __restrict__ out) {
    __shared__ __align__(16) float smem[4 * CIT];
    __shared__ float pbuf[4 * 256];
    __shared__ float rsum[COUT], rsq[COUT];

    const float* xt   = ws + WS_XT;
    const float* offt = ws + WS_OFFT;
    const float* wt   = ws + WS_WT;
    float* gstat = ws + WS_STAT;

    int tid = threadIdx.x;
    int wave = tid >> 6, lane = tid & 63;
    if (tid < COUT) { rsum[tid] = 0.f; rsq[tid] = 0.f; }

    int p = blockIdx.x * 4 + wave;
    int d = p >> 10, h = (p >> 5) & 31, w = p & 31;

    // Preload this voxel's 81 offsets (2 coalesced loads), broadcast via shfl.
    float r0 = offt[p * OFFSTRIDE + lane];
    float r1 = offt[p * OFFSTRIDE + 64 + lane];

    float* sm = smem + wave * CIT;
#pragma unroll
    for (int k = 0; k < KT; k++) {
        const int kd = k / 9, kh = (k / 3) % 3, kw = k % 3;
        const int j = k * 3;
        float od = (j     < 64) ? __shfl(r0, j)     : __shfl(r1, j - 64);
        float oh = (j + 1 < 64) ? __shfl(r0, j + 1) : __shfl(r1, j - 63);
        float ow = (j + 2 < 64) ? __shfl(r0, j + 2) : __shfl(r1, j - 62);
        float pdc = (float)(d + kd - 1) + od;
        float phc = (float)(h + kh - 1) + oh;
        float pwc = (float)(w + kw - 1) + ow;
        float fd0 = floorf(pdc), fh0 = floorf(phc), fw0 = floorf(pwc);
        float fd = pdc - fd0, fh = phc - fh0, fw = pwc - fw0;
        int id = (int)fd0, ih = (int)fh0, iw = (int)fw0;

        int rdx[2], rhx[2], rwx[2];
        float wdx[2] = {1.f - fd, fd}, whx[2] = {1.f - fh, fh}, wwx[2] = {1.f - fw, fw};
#pragma unroll
        for (int t = 0; t < 2; t++) {
            int cd = min(max(id + t, -2), 33);
            rdx[t] = ((cd >> 1) + 1) * (324 * 64);
            int ch = min(max(ih + t, -2), 33);
            rhx[t] = ((ch >> 1) + 1) * (18 * 64);
            int cw = min(max(iw + t, -2), 33);
            rwx[t] = ((cw >> 1) + 1) * 64;
        }
        float sv = 0.f;
#pragma unroll
        for (int dd = 0; dd < 2; dd++)
#pragma unroll
            for (int hh = 0; hh < 2; hh++)
#pragma unroll
                for (int ww2 = 0; ww2 < 2; ww2++)
                    sv += wdx[dd] * whx[hh] * wwx[ww2]
                        * xt[rdx[dd] + rhx[hh] + rwx[ww2] + lane];
        sm[lane * KT + k] = sv;
    }
    __syncthreads();

    // Phase B: o = out channel, slice = 1/8 of K (216 elems = 54 float4s)
    int o = tid & 31, slice = tid >> 5;
    float acc0 = 0.f, acc1 = 0.f, acc2 = 0.f, acc3 = 0.f;
    const float4* wt4 = (const float4*)(wt) + slice * (54 * 32) + o;
    const float4* s4  = (const float4*)(smem) + slice * 54;
    for (int i = 0; i < 54; i++) {
        float4 wv = wt4[i * 32];
        float4 a0 = s4[i];
        float4 a1 = s4[432 + i];
        float4 a2 = s4[864 + i];
        float4 a3 = s4[1296 + i];
        acc0 += wv.x * a0.x + wv.y * a0.y + wv.z * a0.z + wv.w * a0.w;
        acc1 += wv.x * a1.x + wv.y * a1.y + wv.z * a1.z + wv.w * a1.w;
        acc2 += wv.x * a2.x + wv.y * a2.y + wv.z * a2.z + wv.w * a2.w;
        acc3 += wv.x * a3.x + wv.y * a3.y + wv.z * a3.z + wv.w * a3.w;
    }
    pbuf[0 * 256 + tid] = acc0;
    pbuf[1 * 256 + tid] = acc1;
    pbuf[2 * 256 + tid] = acc2;
    pbuf[3 * 256 + tid] = acc3;
    __syncthreads();

    if (tid < 128) {
        int v = tid >> 5, oo = tid & 31;
        float s = 0.f;
#pragma unroll
        for (int sl = 0; sl < 8; sl++) s += pbuf[v * 256 + sl * 32 + oo];
        s += bias[oo];
        out[oo * NVOX + blockIdx.x * 4 + v] = s;
        atomicAdd(&rsum[oo], s);
        atomicAdd(&rsq[oo], s * s);
    }
    __syncthreads();
    if (tid < COUT) {
        atomicAdd(&gstat[tid], rsum[tid]);
        atomicAdd(&gstat[COUT + tid], rsq[tid]);
    }
}

// ---------------------------------------------------------------------------
// BN finalize + ReLU, in-place on d_out.
// ---------------------------------------------------------------------------
__global__ void bn_kernel(const float* __restrict__ ws,
                          const float* __restrict__ gamma,
                          const float* __restrict__ beta,
                          float* out) {
    int i = blockIdx.x * 256 + threadIdx.x;
    int o = i >> 15;
    const float* gstat = ws + WS_STAT;
    const float inv = 1.f / 32768.f;
    float mean = gstat[o] * inv;
    float var  = gstat[COUT + o] * inv - mean * mean;
    float sc   = rsqrtf(var + 1e-5f) * gamma[o];
    float v = (out[i] - mean) * sc + beta[o];
    out[i] = fmaxf(v, 0.f);
}

// ---------------------------------------------------------------------------
extern "C" void kernel_launch(void* const* d_in, const int* in_sizes, int n_in,
                              void* d_out, int out_size, void* d_ws, size_t ws_size,
                              hipStream_t stream) {
    const float* x     = (const float*)d_in[0];
    const float* w_off = (const float*)d_in[1];
    const float* b_off = (const float*)d_in[2];
    const float* wmat  = (const float*)d_in[3];
    const float* bias  = (const float*)d_in[4];
    const float* gamma = (const float*)d_in[5];
    const float* beta  = (const float*)d_in[6];
    float* ws  = (float*)d_ws;
    float* out = (float*)d_out;

    hipMemsetAsync(ws + WS_STAT, 0, 64 * sizeof(float), stream);
    prep_kernel<<<PSP, 64, 0, stream>>>(x, ws);
    wc_prep_kernel<<<dim3(81, 8), 64, 0, stream>>>(w_off, ws);
    wt_prep_kernel<<<216, 256, 0, stream>>>(wmat, ws);
    off_conv_kernel<<<dim3(16, 9, 8), 256, 0, stream>>>(b_off, ws);
    deform_kernel<<<8192, 256, 0, stream>>>(bias, ws, out);
    bn_kernel<<<4096, 256, 0, stream>>>(ws, gamma, beta, out);
}

// Round 3
// 292.279 us; speedup vs baseline: 4.2544x; 1.2533x over previous
//
#include <hip/hip_runtime.h>
#include <math.h>

// Problem constants
#define NVOX  32768     // 32^3 up-res voxels
#define CIN   64
#define COUT  32
#define KT    27
#define CIT   1728      // CIN*KT
#define PSP   5832      // 18^3 padded half-res spatial

// Workspace layout (float offsets)
#define WS_XP   0                 // [64][5832] channel-first padded x
#define WS_XT   373248            // [5832][64] channel-last padded x
#define WS_WC   746496            // [8][81][64][8] parity-collapsed offset weights
#define WS_WA   1078272           // bf16[216][32][8] A-fragment-packed deform weights
#define WS_OFF  1105920           // [81][32768] offsets, kc-major
#define WS_STAT 3760128           // [32] sum, [32] sumsq

#define SST 1736                  // smem voxel-row stride in bf16 (3472B, 16B-aligned)

typedef __attribute__((ext_vector_type(8))) short short8;
typedef __attribute__((ext_vector_type(4))) float floatx4;

static __device__ __forceinline__ unsigned short f2bf(float f) {
    unsigned int u = __float_as_uint(f);
    unsigned int r = (u + 0x7FFF + ((u >> 16) & 1)) >> 16;
    return (unsigned short)r;
}

// ---------------------------------------------------------------------------
// Prep: zero-padded x in two layouts. Padded idx q+1, q in [-1,16].
// ---------------------------------------------------------------------------
__global__ void prep_kernel(const float* __restrict__ x, float* __restrict__ ws) {
    int s = blockIdx.x;          // 0..5831
    int c = threadIdx.x;         // 0..63
    int qw = s % 18, qh = (s / 18) % 18, qd = s / 324;
    float v = 0.f;
    if (qd >= 1 && qd <= 16 && qh >= 1 && qh <= 16 && qw >= 1 && qw <= 16)
        v = x[((c * 16 + (qd - 1)) * 16 + (qh - 1)) * 16 + (qw - 1)];
    ws[WS_XT + s * 64 + c]  = v;
    ws[WS_XP + c * PSP + s] = v;
}

// ---------------------------------------------------------------------------
// Parity-collapse the 27-tap offset-conv weights to 8 taps per parity.
// ---------------------------------------------------------------------------
__global__ void wc_prep_kernel(const float* __restrict__ w_off, float* __restrict__ ws) {
    int kc = blockIdx.x;         // 0..80
    int pi = blockIdx.y;         // 0..7
    int ci = threadIdx.x;        // 0..63
    int pd = (pi >> 2) & 1, ph = (pi >> 1) & 1, pw = pi & 1;
    const float* wsrc = w_off + (kc * 64 + ci) * 27;
    float w3[27];
#pragma unroll
    for (int t = 0; t < 27; t++) w3[t] = wsrc[t];
    float* dst = ws + WS_WC + ((pi * 81 + kc) * 64 + ci) * 8;
#pragma unroll
    for (int cd = 0; cd < 2; cd++) {
        int lod = (cd == 0) ? 0 : (pd == 0 ? 1 : 2);
        int hid = (cd == 0) ? (pd == 0 ? 0 : 1) : 2;
#pragma unroll
        for (int ch = 0; ch < 2; ch++) {
            int loh = (ch == 0) ? 0 : (ph == 0 ? 1 : 2);
            int hih = (ch == 0) ? (ph == 0 ? 0 : 1) : 2;
#pragma unroll
            for (int cw = 0; cw < 2; cw++) {
                int low = (cw == 0) ? 0 : (pw == 0 ? 1 : 2);
                int hiw = (cw == 0) ? (pw == 0 ? 0 : 1) : 2;
                float a = 0.f;
                for (int kd = lod; kd <= hid; kd++)
                    for (int kh = loh; kh <= hih; kh++)
                        for (int kw = low; kw <= hiw; kw++)
                            a += w3[kd * 9 + kh * 3 + kw];
                dst[cd * 4 + ch * 2 + cw] = a;
            }
        }
    }
}

// ---------------------------------------------------------------------------
// Pack deform weights into bf16 A-fragment layout:
// wa[(kb*32 + o)*8 + j] = bf16(wmat[o][kb*8 + j]), kb in [0,216), o in [0,32)
// ---------------------------------------------------------------------------
__global__ void wa_prep_kernel(const float* __restrict__ wmat, float* __restrict__ ws) {
    int idx = blockIdx.x * 256 + threadIdx.x;    // 0..6911
    if (idx >= 216 * 32) return;
    int kb = idx >> 5, o = idx & 31;
    const float* src = wmat + o * CIT + kb * 8;
    unsigned short* wa = (unsigned short*)(ws + WS_WA);
#pragma unroll
    for (int j = 0; j < 8; j++) wa[idx * 8 + j] = f2bf(src[j]);
}

// ---------------------------------------------------------------------------
// Offset conv via parity collapse (2x2x2 on half-res). Output kc-major.
// ---------------------------------------------------------------------------
__global__ __launch_bounds__(256) void off_conv_kernel(
        const float* __restrict__ b_off, float* __restrict__ ws) {
    const float* xp = ws + WS_XP;
    const float* wc = ws + WS_WC;
    float* off = ws + WS_OFF;

    int tid = threadIdx.x;
    int phf = blockIdx.x * 256 + tid;            // half-res voxel 0..4095
    int qw = phf & 15, qh = (phf >> 4) & 15, qd = phf >> 8;
    int pi = blockIdx.z;
    int pd = (pi >> 2) & 1, ph = (pi >> 1) & 1, pw = pi & 1;
    int kc0 = blockIdx.y * 9;

    int base = ((qd + pd) * 18 + (qh + ph)) * 18 + (qw + pw);

    float acc[9];
#pragma unroll
    for (int j = 0; j < 9; j++) acc[j] = b_off[kc0 + j];

    for (int ci = 0; ci < CIN; ci++) {
        const float* xb = xp + ci * PSP + base;
        float xv[8];
        xv[0] = xb[0];   xv[1] = xb[1];
        xv[2] = xb[18];  xv[3] = xb[19];
        xv[4] = xb[324]; xv[5] = xb[325];
        xv[6] = xb[342]; xv[7] = xb[343];
        const float* wrow = wc + ((pi * 81 + kc0) * 64 + ci) * 8;
#pragma unroll
        for (int j = 0; j < 9; j++) {
            const float4* wp = (const float4*)(wrow + j * 512);
            float4 a = wp[0], b = wp[1];
            acc[j] += a.x * xv[0] + a.y * xv[1] + a.z * xv[2] + a.w * xv[3]
                    + b.x * xv[4] + b.y * xv[5] + b.z * xv[6] + b.w * xv[7];
        }
    }
    int d = 2 * qd + pd, h = 2 * qh + ph, w = 2 * qw + pw;
    int p = (d << 10) + (h << 5) + w;
#pragma unroll
    for (int j = 0; j < 9; j++)
        off[(kc0 + j) * NVOX + p] = acc[j];
}

// ---------------------------------------------------------------------------
// Deformable sample + MFMA einsum + BN stats.
// Block = 256 threads = 4 waves = 16 voxels (one contiguous w-strip).
// Phase A: wave gathers 4 voxels (lane=channel), lerp-factored trilinear,
//          bf16 result into LDS S[v][k] (stride 1736).
// Phase B: 16x16x32 bf16 MFMA, M=32 (2 tiles), N=16 voxels, K=1728 split in 2
//          halves across waves; cross-half reduce via LDS.
// ---------------------------------------------------------------------------
__global__ __launch_bounds__(256) void deform_kernel(
        const float* __restrict__ bias, float* ws, float* __restrict__ out) {
    __shared__ __align__(16) unsigned short smem[16 * SST];   // 55552 B
    __shared__ float offl[16 * 84];                           // 5376 B
    __shared__ float pbuf[2][16][16];                         // 2048 B
    __shared__ float rsum[COUT], rsq[COUT];

    const float* xt  = ws + WS_XT;
    const float* off = ws + WS_OFF;
    const unsigned short* wa = (const unsigned short*)(ws + WS_WA);
    float* gstat = ws + WS_STAT;

    int tid = threadIdx.x, wave = tid >> 6, lane = tid & 63;
    int pbase = blockIdx.x * 16;

    if (tid < COUT) { rsum[tid] = 0.f; rsq[tid] = 0.f; }

    // Cooperative offset stage: off[kc][pbase+v] -> offl[v*84+kc] (coalesced 64B)
    for (int idx = tid; idx < 81 * 16; idx += 256) {
        int kc = idx >> 4, v = idx & 15;
        offl[v * 84 + kc] = off[kc * NVOX + pbase + v];
    }
    __syncthreads();

    // -------- Phase A --------
#pragma unroll 1
    for (int vi = 0; vi < 4; vi++) {
        int v = wave * 4 + vi;
        int p = pbase + v;
        int d = p >> 10, h = (p >> 5) & 31, w = p & 31;
        unsigned short* sv_base = smem + v * SST + lane * KT;
        const float* ob = offl + v * 84;
#pragma unroll
        for (int k = 0; k < KT; k++) {
            const int kd = k / 9, kh2 = (k / 3) % 3, kw2 = k % 3;
            float od = ob[3 * k];       // broadcast LDS reads
            float oh = ob[3 * k + 1];
            float ow = ob[3 * k + 2];
            float pdc = (float)(d + kd - 1) + od;
            float phc = (float)(h + kh2 - 1) + oh;
            float pwc = (float)(w + kw2 - 1) + ow;
            float fd0 = floorf(pdc), fh0 = floorf(phc), fw0 = floorf(pwc);
            float fd = pdc - fd0, fh = phc - fh0, fw = pwc - fw0;
            int id = (int)fd0, ih = (int)fh0, iw = (int)fw0;
            int rdx0 = ((min(max(id,     -2), 33) >> 1) + 1) * (324 * 64);
            int rdx1 = ((min(max(id + 1, -2), 33) >> 1) + 1) * (324 * 64);
            int rhx0 = ((min(max(ih,     -2), 33) >> 1) + 1) * (18 * 64);
            int rhx1 = ((min(max(ih + 1, -2), 33) >> 1) + 1) * (18 * 64);
            int rwx0 = ((min(max(iw,     -2), 33) >> 1) + 1) * 64 + lane;
            int rwx1 = ((min(max(iw + 1, -2), 33) >> 1) + 1) * 64 + lane;
            float x000 = xt[rdx0 + rhx0 + rwx0], x001 = xt[rdx0 + rhx0 + rwx1];
            float x010 = xt[rdx0 + rhx1 + rwx0], x011 = xt[rdx0 + rhx1 + rwx1];
            float x100 = xt[rdx1 + rhx0 + rwx0], x101 = xt[rdx1 + rhx0 + rwx1];
            float x110 = xt[rdx1 + rhx1 + rwx0], x111 = xt[rdx1 + rhx1 + rwx1];
            float c00 = x000 + fw * (x001 - x000);
            float c01 = x010 + fw * (x011 - x010);
            float c10 = x100 + fw * (x101 - x100);
            float c11 = x110 + fw * (x111 - x110);
            float c0 = c00 + fh * (c01 - c00);
            float c1 = c10 + fh * (c11 - c10);
            float sv = c0 + fd * (c1 - c0);
            sv_base[k] = f2bf(sv);
        }
    }
    __syncthreads();

    // -------- Phase B: MFMA --------
    int mt = wave & 1, kh = wave >> 1;
    int col = lane & 15, quad = lane >> 4;
    floatx4 acc = {0.f, 0.f, 0.f, 0.f};
    const short8* wa8 = (const short8*)wa;
    for (int s = 0; s < 27; s++) {
        int k = kh * 864 + s * 32;
        int kb = (k >> 3) + quad;
        short8 afrag = wa8[kb * 32 + mt * 16 + col];
        short8 bfrag = *(const short8*)(smem + col * SST + k + quad * 8);
        acc = __builtin_amdgcn_mfma_f32_16x16x32_bf16(afrag, bfrag, acc, 0, 0, 0);
    }
    if (kh == 1) {
#pragma unroll
        for (int r = 0; r < 4; r++) pbuf[mt][quad * 4 + r][col] = acc[r];
    }
    __syncthreads();
    if (kh == 0) {
#pragma unroll
        for (int r = 0; r < 4; r++) {
            int o = mt * 16 + quad * 4 + r;
            float val = acc[r] + pbuf[mt][quad * 4 + r][col] + bias[o];
            out[o * NVOX + pbase + col] = val;
            atomicAdd(&rsum[o], val);
            atomicAdd(&rsq[o], val * val);
        }
    }
    __syncthreads();
    if (tid < COUT) {
        atomicAdd(&gstat[tid], rsum[tid]);
        atomicAdd(&gstat[COUT + tid], rsq[tid]);
    }
}

// ---------------------------------------------------------------------------
// BN finalize + ReLU, in-place on d_out.
// ---------------------------------------------------------------------------
__global__ void bn_kernel(const float* __restrict__ ws,
                          const float* __restrict__ gamma,
                          const float* __restrict__ beta,
                          float* out) {
    int i = blockIdx.x * 256 + threadIdx.x;
    int o = i >> 15;
    const float* gstat = ws + WS_STAT;
    const float inv = 1.f / 32768.f;
    float mean = gstat[o] * inv;
    float var  = gstat[COUT + o] * inv - mean * mean;
    float sc   = rsqrtf(var + 1e-5f) * gamma[o];
    float v = (out[i] - mean) * sc + beta[o];
    out[i] = fmaxf(v, 0.f);
}

// ---------------------------------------------------------------------------
extern "C" void kernel_launch(void* const* d_in, const int* in_sizes, int n_in,
                              void* d_out, int out_size, void* d_ws, size_t ws_size,
                              hipStream_t stream) {
    const float* x     = (const float*)d_in[0];
    const float* w_off = (const float*)d_in[1];
    const float* b_off = (const float*)d_in[2];
    const float* wmat  = (const float*)d_in[3];
    const float* bias  = (const float*)d_in[4];
    const float* gamma = (const float*)d_in[5];
    const float* beta  = (const float*)d_in[6];
    float* ws  = (float*)d_ws;
    float* out = (float*)d_out;

    hipMemsetAsync(ws + WS_STAT, 0, 64 * sizeof(float), stream);
    prep_kernel<<<PSP, 64, 0, stream>>>(x, ws);
    wc_prep_kernel<<<dim3(81, 8), 64, 0, stream>>>(w_off, ws);
    wa_prep_kernel<<<27, 256, 0, stream>>>(wmat, ws);
    off_conv_kernel<<<dim3(16, 9, 8), 256, 0, stream>>>(b_off, ws);
    deform_kernel<<<2048, 256, 0, stream>>>(bias, ws, out);
    bn_kernel<<<4096, 256, 0, stream>>>(ws, gamma, beta, out);
}

// Round 4
// 276.689 us; speedup vs baseline: 4.4941x; 1.0563x over previous
//
#include <hip/hip_runtime.h>
#include <math.h>

// Problem constants
#define NVOX  32768     // 32^3 up-res voxels
#define CIN   64
#define COUT  32
#define KT    27
#define CIT   1728      // CIN*KT
#define PSP   5832      // 18^3 padded half-res spatial

// Workspace layout (float offsets)
#define WS_XP   0                 // [64][5832] channel-first padded x
#define WS_XT   373248            // [5832][64] channel-last padded x
#define WS_WC   746496            // [8][81][64][8] parity-collapsed offset weights
#define WS_WA   1078272           // bf16[216][32][8] A-fragment-packed deform weights
#define WS_OFF  1105920           // [81][32768] offsets, kc-major
#define WS_STAT 3760128           // [32] sum, [32] sumsq

#define SST 1736                  // smem voxel-row stride in bf16 (3472B, 16B-aligned)

typedef __attribute__((ext_vector_type(8))) short short8;
typedef __attribute__((ext_vector_type(4))) float floatx4;

static __device__ __forceinline__ unsigned short f2bf(float f) {
    unsigned int u = __float_as_uint(f);
    unsigned int r = (u + 0x7FFF + ((u >> 16) & 1)) >> 16;
    return (unsigned short)r;
}

// ---------------------------------------------------------------------------
// Merged prep: blocks [0,5832) pad x; [5832,6480) parity-collapse w_off;
// [6480,6507) pack wmat to bf16 A-fragments; block 6507 zeros stats.
// ---------------------------------------------------------------------------
__global__ void prep_all_kernel(const float* __restrict__ x,
                                const float* __restrict__ w_off,
                                const float* __restrict__ wmat,
                                float* __restrict__ ws) {
    int b = blockIdx.x, t = threadIdx.x;
    if (b < 5832) {
        int s = b, c = t;
        int qw = s % 18, qh = (s / 18) % 18, qd = s / 324;
        float v = 0.f;
        if (qd >= 1 && qd <= 16 && qh >= 1 && qh <= 16 && qw >= 1 && qw <= 16)
            v = x[((c * 16 + (qd - 1)) * 16 + (qh - 1)) * 16 + (qw - 1)];
        ws[WS_XT + s * 64 + c]  = v;
        ws[WS_XP + c * PSP + s] = v;
    } else if (b < 6480) {
        int bb = b - 5832;
        int kc = bb % 81, pi = bb / 81, ci = t;
        int pd = (pi >> 2) & 1, ph = (pi >> 1) & 1, pw = pi & 1;
        const float* wsrc = w_off + (kc * 64 + ci) * 27;
        float w3[27];
#pragma unroll
        for (int tt = 0; tt < 27; tt++) w3[tt] = wsrc[tt];
        float* dst = ws + WS_WC + ((pi * 81 + kc) * 64 + ci) * 8;
#pragma unroll
        for (int cd = 0; cd < 2; cd++) {
            int lod = (cd == 0) ? 0 : (pd == 0 ? 1 : 2);
            int hid = (cd == 0) ? (pd == 0 ? 0 : 1) : 2;
#pragma unroll
            for (int ch = 0; ch < 2; ch++) {
                int loh = (ch == 0) ? 0 : (ph == 0 ? 1 : 2);
                int hih = (ch == 0) ? (ph == 0 ? 0 : 1) : 2;
#pragma unroll
                for (int cw = 0; cw < 2; cw++) {
                    int low = (cw == 0) ? 0 : (pw == 0 ? 1 : 2);
                    int hiw = (cw == 0) ? (pw == 0 ? 0 : 1) : 2;
                    float a = 0.f;
                    for (int kd = lod; kd <= hid; kd++)
                        for (int kh = loh; kh <= hih; kh++)
                            for (int kw = low; kw <= hiw; kw++)
                                a += w3[kd * 9 + kh * 3 + kw];
                    dst[cd * 4 + ch * 2 + cw] = a;
                }
            }
        }
    } else if (b < 6507) {
        unsigned short* wa = (unsigned short*)(ws + WS_WA);
        int idx4 = ((b - 6480) * 64 + t) * 4;
#pragma unroll
        for (int m = 0; m < 4; m++) {
            int idx = idx4 + m;                 // 0..6911
            int kb = idx >> 5, o = idx & 31;
            const float* src = wmat + o * CIT + kb * 8;
#pragma unroll
            for (int j = 0; j < 8; j++) wa[idx * 8 + j] = f2bf(src[j]);
        }
    } else {
        ws[WS_STAT + t] = 0.f;                  // t in [0,64): sum + sumsq
    }
}

// ---------------------------------------------------------------------------
// Offset conv via parity collapse (2x2x2 on half-res), 2 voxels per thread
// along w: 12 loads feed 2 outputs per weight fetch. Output kc-major.
// ---------------------------------------------------------------------------
__global__ __launch_bounds__(256) void off_conv_kernel(
        const float* __restrict__ b_off, float* __restrict__ ws) {
    const float* xp = ws + WS_XP;
    const float* wc = ws + WS_WC;
    float* off = ws + WS_OFF;

    int tid = threadIdx.x;
    int t2 = blockIdx.x * 256 + tid;             // 0..2047 = pair of half-voxels
    int j8 = t2 & 7, qh = (t2 >> 3) & 15, qd = t2 >> 7;
    int qw0 = j8 * 2;
    int pi = blockIdx.z;
    int pd = (pi >> 2) & 1, ph = (pi >> 1) & 1, pw = pi & 1;
    int kc0 = blockIdx.y * 9;

    int base = ((qd + pd) * 18 + (qh + ph)) * 18 + (qw0 + pw);

    float accA[9], accB[9];
#pragma unroll
    for (int j = 0; j < 9; j++) { accA[j] = b_off[kc0 + j]; accB[j] = accA[j]; }

    for (int ci = 0; ci < CIN; ci++) {
        const float* xb = xp + ci * PSP + base;
        float c0 = xb[0],   c1 = xb[1],   c2 = xb[2];
        float c3 = xb[18],  c4 = xb[19],  c5 = xb[20];
        float c6 = xb[324], c7 = xb[325], c8 = xb[326];
        float c9 = xb[342], c10 = xb[343], c11 = xb[344];
        const float* wrow = wc + ((pi * 81 + kc0) * 64 + ci) * 8;
#pragma unroll
        for (int j = 0; j < 9; j++) {
            const float4* wp = (const float4*)(wrow + j * 512);
            float4 a = wp[0], b2 = wp[1];
            accA[j] += a.x * c0 + a.y * c1 + a.z * c3 + a.w * c4
                     + b2.x * c6 + b2.y * c7 + b2.z * c9 + b2.w * c10;
            accB[j] += a.x * c1 + a.y * c2 + a.z * c4 + a.w * c5
                     + b2.x * c7 + b2.y * c8 + b2.z * c10 + b2.w * c11;
        }
    }
    int d = 2 * qd + pd, h = 2 * qh + ph;
    int wA = 2 * qw0 + pw;
    int pA = (d << 10) + (h << 5) + wA;
#pragma unroll
    for (int j = 0; j < 9; j++) {
        off[(kc0 + j) * NVOX + pA]     = accA[j];
        off[(kc0 + j) * NVOX + pA + 2] = accB[j];
    }
}

// ---------------------------------------------------------------------------
// Deformable sample + MFMA einsum + BN stats.
// Block = 256 threads = 4 waves = 16 voxels (one contiguous w-strip).
// 3 groups of 9 taps:
//   Stage0 (144 threads): per (voxel,tap) item compute 8 corner element
//          indices + 8 trilinear corner weights -> LDS (dedups the 64x
//          lane-redundant coordinate math of R3).
//   Gather (4 waves, lane=channel): per tap 4 broadcast b128 LDS reads,
//          8 coalesced global loads, 8 fma, bf16 pack -> S in LDS.
// Phase B: 16x16x32 bf16 MFMA, M=32 (2 tiles), N=16 voxels, K=1728 split in 2
//          halves across waves; cross-half reduce via LDS.
// ---------------------------------------------------------------------------
__global__ __launch_bounds__(256) void deform_kernel(
        const float* __restrict__ bias, float* ws, float* __restrict__ out) {
    __shared__ __align__(16) unsigned short smem[16 * SST];   // 55552 B
    __shared__ __align__(16) int   cba[144 * 8];              // 4608 B
    __shared__ __align__(16) float cbw[144 * 8];              // 4608 B
    __shared__ float pbuf[2][16][16];                         // 2048 B
    __shared__ float rsum[COUT], rsq[COUT];

    const float* xt  = ws + WS_XT;
    const float* off = ws + WS_OFF;
    const unsigned short* wa = (const unsigned short*)(ws + WS_WA);
    float* gstat = ws + WS_STAT;

    int tid = threadIdx.x, wave = tid >> 6, lane = tid & 63;
    int pbase = blockIdx.x * 16;

    if (tid < COUT) { rsum[tid] = 0.f; rsq[tid] = 0.f; }

#pragma unroll 1
    for (int g = 0; g < 3; g++) {
        if (g) __syncthreads();         // coord buffer reuse hazard
        if (tid < 144) {
            int v = tid & 15, tl = tid >> 4;
            int tap = g * 9 + tl;
            int kd = tap / 9, kh2 = (tap / 3) % 3, kw2 = tap % 3;
            int p = pbase + v;
            int d = p >> 10, h = (p >> 5) & 31, w = p & 31;
            float od = off[(3 * tap + 0) * NVOX + p];
            float oh = off[(3 * tap + 1) * NVOX + p];
            float ow = off[(3 * tap + 2) * NVOX + p];
            float pdc = (float)(d + kd - 1) + od;
            float phc = (float)(h + kh2 - 1) + oh;
            float pwc = (float)(w + kw2 - 1) + ow;
            float fd0 = floorf(pdc), fh0 = floorf(phc), fw0 = floorf(pwc);
            float fd = pdc - fd0, fh = phc - fh0, fw = pwc - fw0;
            int id = (int)fd0, ih = (int)fh0, iw = (int)fw0;
            int rd0 = ((min(max(id,     -2), 33) >> 1) + 1) * (324 * 64);
            int rd1 = ((min(max(id + 1, -2), 33) >> 1) + 1) * (324 * 64);
            int rh0 = ((min(max(ih,     -2), 33) >> 1) + 1) * (18 * 64);
            int rh1 = ((min(max(ih + 1, -2), 33) >> 1) + 1) * (18 * 64);
            int rw0 = ((min(max(iw,     -2), 33) >> 1) + 1) * 64;
            int rw1 = ((min(max(iw + 1, -2), 33) >> 1) + 1) * 64;
            int* A = cba + tid * 8;
            float* W = cbw + tid * 8;
            A[0] = rd0 + rh0 + rw0; A[1] = rd0 + rh0 + rw1;
            A[2] = rd0 + rh1 + rw0; A[3] = rd0 + rh1 + rw1;
            A[4] = rd1 + rh0 + rw0; A[5] = rd1 + rh0 + rw1;
            A[6] = rd1 + rh1 + rw0; A[7] = rd1 + rh1 + rw1;
            float gd = 1.f - fd, gh = 1.f - fh, gw = 1.f - fw;
            W[0] = gd * gh * gw; W[1] = gd * gh * fw;
            W[2] = gd * fh * gw; W[3] = gd * fh * fw;
            W[4] = fd * gh * gw; W[5] = fd * gh * fw;
            W[6] = fd * fh * gw; W[7] = fd * fh * fw;
        }
        __syncthreads();

#pragma unroll
        for (int vi = 0; vi < 4; vi++) {
            int v = wave * 4 + vi;
            unsigned short* sb = smem + v * SST + lane * KT + g * 9;
#pragma unroll
            for (int tl = 0; tl < 9; tl++) {
                int item = tl * 16 + v;
                const int4*   a4 = (const int4*)(cba + item * 8);
                const float4* w4 = (const float4*)(cbw + item * 8);
                int4 a0 = a4[0], a1 = a4[1];
                float4 w0 = w4[0], w1 = w4[1];
                float s = w0.x * xt[a0.x + lane] + w0.y * xt[a0.y + lane]
                        + w0.z * xt[a0.z + lane] + w0.w * xt[a0.w + lane]
                        + w1.x * xt[a1.x + lane] + w1.y * xt[a1.y + lane]
                        + w1.z * xt[a1.z + lane] + w1.w * xt[a1.w + lane];
                sb[tl] = f2bf(s);
            }
        }
    }
    __syncthreads();

    // -------- Phase B: MFMA --------
    int mt = wave & 1, kh = wave >> 1;
    int col = lane & 15, quad = lane >> 4;
    floatx4 acc = {0.f, 0.f, 0.f, 0.f};
    const short8* wa8 = (const short8*)wa;
    for (int s = 0; s < 27; s++) {
        int k = kh * 864 + s * 32;
        int kb = (k >> 3) + quad;
        short8 afrag = wa8[kb * 32 + mt * 16 + col];
        short8 bfrag = *(const short8*)(smem + col * SST + k + quad * 8);
        acc = __builtin_amdgcn_mfma_f32_16x16x32_bf16(afrag, bfrag, acc, 0, 0, 0);
    }
    if (kh == 1) {
#pragma unroll
        for (int r = 0; r < 4; r++) pbuf[mt][quad * 4 + r][col] = acc[r];
    }
    __syncthreads();
    if (kh == 0) {
#pragma unroll
        for (int r = 0; r < 4; r++) {
            int o = mt * 16 + quad * 4 + r;
            float val = acc[r] + pbuf[mt][quad * 4 + r][col] + bias[o];
            out[o * NVOX + pbase + col] = val;
            atomicAdd(&rsum[o], val);
            atomicAdd(&rsq[o], val * val);
        }
    }
    __syncthreads();
    if (tid < COUT) {
        atomicAdd(&gstat[tid], rsum[tid]);
        atomicAdd(&gstat[COUT + tid], rsq[tid]);
    }
}

// ---------------------------------------------------------------------------
// BN finalize + ReLU, in-place on d_out.
// ---------------------------------------------------------------------------
__global__ void bn_kernel(const float* __restrict__ ws,
                          const float* __restrict__ gamma,
                          const float* __restrict__ beta,
                          float* out) {
    int i = blockIdx.x * 256 + threadIdx.x;
    int o = i >> 15;
    const float* gstat = ws + WS_STAT;
    const float inv = 1.f / 32768.f;
    float mean = gstat[o] * inv;
    float var  = gstat[COUT + o] * inv - mean * mean;
    float sc   = rsqrtf(var + 1e-5f) * gamma[o];
    float v = (out[i] - mean) * sc + beta[o];
    out[i] = fmaxf(v, 0.f);
}

// ---------------------------------------------------------------------------
extern "C" void kernel_launch(void* const* d_in, const int* in_sizes, int n_in,
                              void* d_out, int out_size, void* d_ws, size_t ws_size,
                              hipStream_t stream) {
    const float* x     = (const float*)d_in[0];
    const float* w_off = (const float*)d_in[1];
    const float* b_off = (const float*)d_in[2];
    const float* wmat  = (const float*)d_in[3];
    const float* bias  = (const float*)d_in[4];
    const float* gamma = (const float*)d_in[5];
    const float* beta  = (const float*)d_in[6];
    float* ws  = (float*)d_ws;
    float* out = (float*)d_out;

    prep_all_kernel<<<6508, 64, 0, stream>>>(x, w_off, wmat, ws);
    off_conv_kernel<<<dim3(8, 9, 8), 256, 0, stream>>>(b_off, ws);
    deform_kernel<<<2048, 256, 0, stream>>>(bias, ws, out);
    bn_kernel<<<4096, 256, 0, stream>>>(ws, gamma, beta, out);
}

// Round 5
// 236.960 us; speedup vs baseline: 5.2476x; 1.1677x over previous
//
#include <hip/hip_runtime.h>
#include <math.h>

// Problem constants
#define NVOX  32768     // 32^3 up-res voxels
#define CIN   64
#define COUT  32
#define KT    27
#define CIT   1728      // CIN*KT
#define PSP   5832      // 18^3 padded half-res spatial

// Workspace layout (float offsets)
#define WS_XP   0                 // [64][5832] channel-first padded x
#define WS_XT   373248            // [5832][64] channel-last padded x
#define WS_WC   746496            // [8][81][64][8] parity-collapsed offset weights
#define WS_WA   1078272           // bf16[216][32][8] A-frag deform weights (K tap-major)
#define WS_OFF  1105920           // [81][32768] offsets, kc-major
#define WS_STAT 3760128           // [32] sum, [32] sumsq

#define SST 584                   // S chunk row stride in u16 (1168 B: 16B-aligned, 4-bank col skew)

typedef __attribute__((ext_vector_type(8))) short short8;
typedef __attribute__((ext_vector_type(4))) float floatx4;

static __device__ __forceinline__ unsigned short f2bf(float f) {
    unsigned int u = __float_as_uint(f);
    unsigned int r = (u + 0x7FFF + ((u >> 16) & 1)) >> 16;
    return (unsigned short)r;
}

// ---------------------------------------------------------------------------
// Merged prep: blocks [0,5832) pad x; [5832,6480) parity-collapse w_off;
// [6480,6507) pack wmat to bf16 A-fragments (K dim tap-major: kk = tap*64+ci);
// block 6507 zeros stats.
// ---------------------------------------------------------------------------
__global__ void prep_all_kernel(const float* __restrict__ x,
                                const float* __restrict__ w_off,
                                const float* __restrict__ wmat,
                                float* __restrict__ ws) {
    int b = blockIdx.x, t = threadIdx.x;
    if (b < 5832) {
        int s = b, c = t;
        int qw = s % 18, qh = (s / 18) % 18, qd = s / 324;
        float v = 0.f;
        if (qd >= 1 && qd <= 16 && qh >= 1 && qh <= 16 && qw >= 1 && qw <= 16)
            v = x[((c * 16 + (qd - 1)) * 16 + (qh - 1)) * 16 + (qw - 1)];
        ws[WS_XT + s * 64 + c]  = v;
        ws[WS_XP + c * PSP + s] = v;
    } else if (b < 6480) {
        int bb = b - 5832;
        int kc = bb % 81, pi = bb / 81, ci = t;
        int pd = (pi >> 2) & 1, ph = (pi >> 1) & 1, pw = pi & 1;
        const float* wsrc = w_off + (kc * 64 + ci) * 27;
        float w3[27];
#pragma unroll
        for (int tt = 0; tt < 27; tt++) w3[tt] = wsrc[tt];
        float* dst = ws + WS_WC + ((pi * 81 + kc) * 64 + ci) * 8;
#pragma unroll
        for (int cd = 0; cd < 2; cd++) {
            int lod = (cd == 0) ? 0 : (pd == 0 ? 1 : 2);
            int hid = (cd == 0) ? (pd == 0 ? 0 : 1) : 2;
#pragma unroll
            for (int ch = 0; ch < 2; ch++) {
                int loh = (ch == 0) ? 0 : (ph == 0 ? 1 : 2);
                int hih = (ch == 0) ? (ph == 0 ? 0 : 1) : 2;
#pragma unroll
                for (int cw = 0; cw < 2; cw++) {
                    int low = (cw == 0) ? 0 : (pw == 0 ? 1 : 2);
                    int hiw = (cw == 0) ? (pw == 0 ? 0 : 1) : 2;
                    float a = 0.f;
                    for (int kd = lod; kd <= hid; kd++)
                        for (int kh = loh; kh <= hih; kh++)
                            for (int kw = low; kw <= hiw; kw++)
                                a += w3[kd * 9 + kh * 3 + kw];
                    dst[cd * 4 + ch * 2 + cw] = a;
                }
            }
        }
    } else if (b < 6507) {
        unsigned short* wa = (unsigned short*)(ws + WS_WA);
        int idx4 = ((b - 6480) * 64 + t) * 4;
#pragma unroll
        for (int m = 0; m < 4; m++) {
            int idx = idx4 + m;                 // 0..6911  (kb, o)
            int kb = idx >> 5, o = idx & 31;
#pragma unroll
            for (int j = 0; j < 8; j++) {
                int kk = kb * 8 + j;            // K index, tap-major
                int tap = kk >> 6, ci = kk & 63;
                wa[idx * 8 + j] = f2bf(wmat[o * CIT + ci * 27 + tap]);
            }
        }
    } else {
        ws[WS_STAT + t] = 0.f;                  // t in [0,64): sum + sumsq
    }
}

// ---------------------------------------------------------------------------
// Offset conv via parity collapse (2x2x2 on half-res), 2 voxels per thread
// along w; 3 kc per block (grid.y=27) for 3x block-level parallelism.
// ---------------------------------------------------------------------------
__global__ __launch_bounds__(256) void off_conv_kernel(
        const float* __restrict__ b_off, float* __restrict__ ws) {
    const float* xp = ws + WS_XP;
    const float* wc = ws + WS_WC;
    float* off = ws + WS_OFF;

    int tid = threadIdx.x;
    int t2 = blockIdx.x * 256 + tid;             // 0..2047 = pair of half-voxels
    int j8 = t2 & 7, qh = (t2 >> 3) & 15, qd = t2 >> 7;
    int qw0 = j8 * 2;
    int pi = blockIdx.z;
    int pd = (pi >> 2) & 1, ph = (pi >> 1) & 1, pw = pi & 1;
    int kc0 = blockIdx.y * 3;

    int base = ((qd + pd) * 18 + (qh + ph)) * 18 + (qw0 + pw);

    float accA[3], accB[3];
#pragma unroll
    for (int j = 0; j < 3; j++) { accA[j] = b_off[kc0 + j]; accB[j] = accA[j]; }

    for (int ci = 0; ci < CIN; ci++) {
        const float* xb = xp + ci * PSP + base;
        float c0 = xb[0],   c1 = xb[1],   c2 = xb[2];
        float c3 = xb[18],  c4 = xb[19],  c5 = xb[20];
        float c6 = xb[324], c7 = xb[325], c8 = xb[326];
        float c9 = xb[342], c10 = xb[343], c11 = xb[344];
        const float* wrow = wc + ((pi * 81 + kc0) * 64 + ci) * 8;
#pragma unroll
        for (int j = 0; j < 3; j++) {
            const float4* wp = (const float4*)(wrow + j * 512);
            float4 a = wp[0], b2 = wp[1];
            accA[j] += a.x * c0 + a.y * c1 + a.z * c3 + a.w * c4
                     + b2.x * c6 + b2.y * c7 + b2.z * c9 + b2.w * c10;
            accB[j] += a.x * c1 + a.y * c2 + a.z * c4 + a.w * c5
                     + b2.x * c7 + b2.y * c8 + b2.z * c10 + b2.w * c11;
        }
    }
    int d = 2 * qd + pd, h = 2 * qh + ph;
    int wA = 2 * qw0 + pw;
    int pA = (d << 10) + (h << 5) + wA;
#pragma unroll
    for (int j = 0; j < 3; j++) {
        off[(kc0 + j) * NVOX + pA]     = accA[j];
        off[(kc0 + j) * NVOX + pA + 2] = accB[j];
    }
}

// ---------------------------------------------------------------------------
// Deformable sample + MFMA einsum + BN stats.
// Block = 256 threads = 4 waves = 16 voxels (one contiguous w-strip).
// 3 groups of 9 taps (K-chunk = 576, tap-major):
//   Stage0 (144 threads): per (voxel,tap) corner indices + weights -> LDS.
//   Gather (4 waves, lane=channel): 8 coalesced global loads + 8 fma ->
//          bf16 S[v][tap_l*64+c] (lane-stride-1 writes: conflict-free).
//   MFMA:  per group, 16x16x32, M=32 (2 tiles) x K=576 split in 2 halves
//          across waves; 9 MFMA/wave/group; cross-half reduce at end.
// LDS ~30 KB -> 5 blocks/CU (vs 67 KB / 2 blocks in R4).
// ---------------------------------------------------------------------------
__global__ __launch_bounds__(256) void deform_kernel(
        const float* __restrict__ bias, float* ws, float* __restrict__ out) {
    __shared__ __align__(16) unsigned short smem[16 * SST];   // 18688 B
    __shared__ __align__(16) int   cba[144 * 8];              // 4608 B
    __shared__ __align__(16) float cbw[144 * 8];              // 4608 B
    __shared__ float pbuf[2][16][16];                         // 2048 B
    __shared__ float rsum[COUT], rsq[COUT];

    const float* xt  = ws + WS_XT;
    const float* off = ws + WS_OFF;
    const unsigned short* wa = (const unsigned short*)(ws + WS_WA);
    float* gstat = ws + WS_STAT;

    int tid = threadIdx.x, wave = tid >> 6, lane = tid & 63;
    int pbase = blockIdx.x * 16;

    if (tid < COUT) { rsum[tid] = 0.f; rsq[tid] = 0.f; }

    int mt = wave & 1, kh = wave >> 1;
    int col = lane & 15, quad = lane >> 4;
    floatx4 acc = {0.f, 0.f, 0.f, 0.f};
    const short8* wa8 = (const short8*)wa;

#pragma unroll 1
    for (int g = 0; g < 3; g++) {
        // ---- Stage0: coord dedup (cba/cbw free: prior gather reads done) ----
        if (tid < 144) {
            int v = tid & 15, tl = tid >> 4;
            int tap = g * 9 + tl;
            int kd = tap / 9, kh2 = (tap / 3) % 3, kw2 = tap % 3;
            int p = pbase + v;
            int d = p >> 10, h = (p >> 5) & 31, w = p & 31;
            float od = off[(3 * tap + 0) * NVOX + p];
            float oh = off[(3 * tap + 1) * NVOX + p];
            float ow = off[(3 * tap + 2) * NVOX + p];
            float pdc = (float)(d + kd - 1) + od;
            float phc = (float)(h + kh2 - 1) + oh;
            float pwc = (float)(w + kw2 - 1) + ow;
            float fd0 = floorf(pdc), fh0 = floorf(phc), fw0 = floorf(pwc);
            float fd = pdc - fd0, fh = phc - fh0, fw = pwc - fw0;
            int id = (int)fd0, ih = (int)fh0, iw = (int)fw0;
            int rd0 = ((min(max(id,     -2), 33) >> 1) + 1) * (324 * 64);
            int rd1 = ((min(max(id + 1, -2), 33) >> 1) + 1) * (324 * 64);
            int rh0 = ((min(max(ih,     -2), 33) >> 1) + 1) * (18 * 64);
            int rh1 = ((min(max(ih + 1, -2), 33) >> 1) + 1) * (18 * 64);
            int rw0 = ((min(max(iw,     -2), 33) >> 1) + 1) * 64;
            int rw1 = ((min(max(iw + 1, -2), 33) >> 1) + 1) * 64;
            int* A = cba + tid * 8;
            float* W = cbw + tid * 8;
            A[0] = rd0 + rh0 + rw0; A[1] = rd0 + rh0 + rw1;
            A[2] = rd0 + rh1 + rw0; A[3] = rd0 + rh1 + rw1;
            A[4] = rd1 + rh0 + rw0; A[5] = rd1 + rh0 + rw1;
            A[6] = rd1 + rh1 + rw0; A[7] = rd1 + rh1 + rw1;
            float gd = 1.f - fd, gh = 1.f - fh, gw = 1.f - fw;
            W[0] = gd * gh * gw; W[1] = gd * gh * fw;
            W[2] = gd * fh * gw; W[3] = gd * fh * fw;
            W[4] = fd * gh * gw; W[5] = fd * gh * fw;
            W[6] = fd * fh * gw; W[7] = fd * fh * fw;
        }
        __syncthreads();   // coords ready; prior MFMA S-reads done -> S reusable

        // ---- Gather: S[v][tl*64 + lane] (bf16, coalesced LDS writes) ----
#pragma unroll
        for (int vi = 0; vi < 4; vi++) {
            int v = wave * 4 + vi;
            unsigned short* sb = smem + v * SST + lane;
#pragma unroll
            for (int tl = 0; tl < 9; tl++) {
                int item = tl * 16 + v;
                const int4*   a4 = (const int4*)(cba + item * 8);
                const float4* w4 = (const float4*)(cbw + item * 8);
                int4 a0 = a4[0], a1 = a4[1];
                float4 w0 = w4[0], w1 = w4[1];
                float s = w0.x * xt[a0.x + lane] + w0.y * xt[a0.y + lane]
                        + w0.z * xt[a0.z + lane] + w0.w * xt[a0.w + lane]
                        + w1.x * xt[a1.x + lane] + w1.y * xt[a1.y + lane]
                        + w1.z * xt[a1.z + lane] + w1.w * xt[a1.w + lane];
                sb[tl * 64] = f2bf(s);
            }
        }
        __syncthreads();   // S chunk ready

        // ---- MFMA over this K-chunk (576), split across kh halves ----
#pragma unroll
        for (int s = 0; s < 9; s++) {
            int k_local = kh * 288 + s * 32;
            int kb = ((g * 576 + k_local) >> 3) + quad;
            short8 afrag = wa8[kb * 32 + mt * 16 + col];
            short8 bfrag = *(const short8*)(smem + col * SST + k_local + quad * 8);
            acc = __builtin_amdgcn_mfma_f32_16x16x32_bf16(afrag, bfrag, acc, 0, 0, 0);
        }
    }

    if (kh == 1) {
#pragma unroll
        for (int r = 0; r < 4; r++) pbuf[mt][quad * 4 + r][col] = acc[r];
    }
    __syncthreads();
    if (kh == 0) {
#pragma unroll
        for (int r = 0; r < 4; r++) {
            int o = mt * 16 + quad * 4 + r;
            float val = acc[r] + pbuf[mt][quad * 4 + r][col] + bias[o];
            out[o * NVOX + pbase + col] = val;
            atomicAdd(&rsum[o], val);
            atomicAdd(&rsq[o], val * val);
        }
    }
    __syncthreads();
    if (tid < COUT) {
        atomicAdd(&gstat[tid], rsum[tid]);
        atomicAdd(&gstat[COUT + tid], rsq[tid]);
    }
}

// ---------------------------------------------------------------------------
// BN finalize + ReLU, in-place on d_out.
// ---------------------------------------------------------------------------
__global__ void bn_kernel(const float* __restrict__ ws,
                          const float* __restrict__ gamma,
                          const float* __restrict__ beta,
                          float* out) {
    int i = blockIdx.x * 256 + threadIdx.x;
    int o = i >> 15;
    const float* gstat = ws + WS_STAT;
    const float inv = 1.f / 32768.f;
    float mean = gstat[o] * inv;
    float var  = gstat[COUT + o] * inv - mean * mean;
    float sc   = rsqrtf(var + 1e-5f) * gamma[o];
    float v = (out[i] - mean) * sc + beta[o];
    out[i] = fmaxf(v, 0.f);
}

// ---------------------------------------------------------------------------
extern "C" void kernel_launch(void* const* d_in, const int* in_sizes, int n_in,
                              void* d_out, int out_size, void* d_ws, size_t ws_size,
                              hipStream_t stream) {
    const float* x     = (const float*)d_in[0];
    const float* w_off = (const float*)d_in[1];
    const float* b_off = (const float*)d_in[2];
    const float* wmat  = (const float*)d_in[3];
    const float* bias  = (const float*)d_in[4];
    const float* gamma = (const float*)d_in[5];
    const float* beta  = (const float*)d_in[6];
    float* ws  = (float*)d_ws;
    float* out = (float*)d_out;

    prep_all_kernel<<<6508, 64, 0, stream>>>(x, w_off, wmat, ws);
    off_conv_kernel<<<dim3(8, 27, 8), 256, 0, stream>>>(b_off, ws);
    deform_kernel<<<2048, 256, 0, stream>>>(bias, ws, out);
    bn_kernel<<<4096, 256, 0, stream>>>(ws, gamma, beta, out);
}

// Round 6
// 196.814 us; speedup vs baseline: 6.3180x; 1.2040x over previous
//
#include <hip/hip_runtime.h>
#include <math.h>

// Problem constants
#define NVOX  32768     // 32^3 up-res voxels
#define CIN   64
#define COUT  32
#define KT    27
#define CIT   1728      // CIN*KT
#define PSP   5832      // 18^3 padded half-res spatial

// Workspace layout (float offsets)
#define WS_XT   0                 // [5832][64] channel-last padded x (fp32)
#define WS_WA   373248            // bf16[216][32][8] deform-W A-frags (K tap-major)
#define WS_WO   400896            // bf16[216][96][8] offset-W A-frags (K tap-major, M padded 81->96)
#define WS_STAT 483840            // [32] sum, [32] sumsq

#define SST 584                   // S chunk row stride in u16 (1168 B)

typedef __attribute__((ext_vector_type(8))) short short8;
typedef __attribute__((ext_vector_type(4))) float floatx4;

static __device__ __forceinline__ unsigned short f2bf(float f) {
    unsigned int u = __float_as_uint(f);
    unsigned int r = (u + 0x7FFF + ((u >> 16) & 1)) >> 16;
    return (unsigned short)r;
}

// ---------------------------------------------------------------------------
// Merged prep:
//   blocks [0,5832):    pad x channel-last -> XT
//   blocks [5832,5859): pack wmat  -> WA  bf16 A-frags (K = tap*64+ci)
//   blocks [5859,5940): pack w_off -> WO  bf16 A-frags (M=96, rows 81..95 = 0)
//   block  5940:        zero stats
// ---------------------------------------------------------------------------
__global__ void prep_all_kernel(const float* __restrict__ x,
                                const float* __restrict__ w_off,
                                const float* __restrict__ wmat,
                                float* __restrict__ ws) {
    int b = blockIdx.x, t = threadIdx.x;
    if (b < 5832) {
        int s = b, c = t;
        int qw = s % 18, qh = (s / 18) % 18, qd = s / 324;
        float v = 0.f;
        if (qd >= 1 && qd <= 16 && qh >= 1 && qh <= 16 && qw >= 1 && qw <= 16)
            v = x[((c * 16 + (qd - 1)) * 16 + (qh - 1)) * 16 + (qw - 1)];
        ws[WS_XT + s * 64 + c] = v;
    } else if (b < 5859) {
        unsigned short* wa = (unsigned short*)(ws + WS_WA);
        int idx4 = ((b - 5832) * 64 + t) * 4;
#pragma unroll
        for (int m = 0; m < 4; m++) {
            int idx = idx4 + m;                 // 0..6911  (kb, o)
            int kb = idx >> 5, o = idx & 31;
#pragma unroll
            for (int j = 0; j < 8; j++) {
                int kk = kb * 8 + j;            // K index, tap-major
                int tap = kk >> 6, ci = kk & 63;
                wa[idx * 8 + j] = f2bf(wmat[o * CIT + ci * 27 + tap]);
            }
        }
    } else if (b < 5940) {
        unsigned short* wo = (unsigned short*)(ws + WS_WO);
        int idx4 = ((b - 5859) * 64 + t) * 4;
#pragma unroll
        for (int mm = 0; mm < 4; mm++) {
            int idx = idx4 + mm;                // 0..20735 = kb*96 + m
            int kb = idx / 96, m = idx % 96;
#pragma unroll
            for (int j = 0; j < 8; j++) {
                int kk = kb * 8 + j;
                int tap = kk >> 6, ci = kk & 63;
                float v = (m < 81) ? w_off[(m * 64 + ci) * 27 + tap] : 0.f;
                wo[idx * 8 + j] = f2bf(v);
            }
        }
    } else {
        ws[WS_STAT + t] = 0.f;                  // t in [0,64): sum + sumsq
    }
}

// ---------------------------------------------------------------------------
// Fused offset-GEMM + deformable sample + deform-GEMM + BN stats.
// Block = 256 threads = 4 waves = 16 voxels (contiguous w-strip).
//
// Phase 0 (offset conv as MFMA GEMM, M=96(81) x N=16 x K=1728):
//   B-gather: per (v,tap) ONE cell index (no interpolation) -> coalesced
//             64-ch load -> bf16 S chunk; 3 groups of 9 taps.
//   MFMA: wave=(kh K-half, mh M-half of 48=3 tiles); 9 steps x 3 tiles/group.
//   Reduce K-halves via LDS -> off_l[81][16] stays in LDS.
// Phase 1 (R5 structure): stage0 coord dedup reads off_l from LDS; gather
//   8-corner trilinear; MFMA M=32 x N=16 x K=1728; epilogue + BN atomics.
// LDS 34.3 KB -> 4 blocks/CU. Pl buffer = P-reduce, then off_l, then pbuf.
// ---------------------------------------------------------------------------
__global__ __launch_bounds__(256) void deform_kernel(
        const float* __restrict__ b_off, const float* __restrict__ bias,
        float* ws, float* __restrict__ out) {
    __shared__ __align__(16) unsigned short smem[16 * SST];   // 18688 B
    __shared__ __align__(16) float Pl[96 * 16];               // 6144 B
    __shared__ __align__(16) int   cba[144 * 8];              // 4608 B
    __shared__ __align__(16) float cbw[144 * 8];              // 4608 B
    __shared__ float rsum[COUT], rsq[COUT];

    const float* xt = ws + WS_XT;
    const unsigned short* wa = (const unsigned short*)(ws + WS_WA);
    const unsigned short* wo = (const unsigned short*)(ws + WS_WO);
    float* gstat = ws + WS_STAT;

    int tid = threadIdx.x, wave = tid >> 6, lane = tid & 63;
    int pbase = blockIdx.x * 16;
    int d = pbase >> 10, h = (pbase >> 5) & 31, w0 = pbase & 31;

    if (tid < COUT) { rsum[tid] = 0.f; rsq[tid] = 0.f; }

    int mh = wave & 1, kh = wave >> 1;      // phase0: M-half / K-half
    int col = lane & 15, quad = lane >> 4;

    // ================= Phase 0: offset GEMM =================
    floatx4 oacc0 = {0.f,0.f,0.f,0.f}, oacc1 = {0.f,0.f,0.f,0.f}, oacc2 = {0.f,0.f,0.f,0.f};
    const short8* wo8 = (const short8*)wo;
#pragma unroll 1
    for (int g = 0; g < 3; g++) {
        if (g) __syncthreads();             // prior MFMA S-reads done
        // B-gather: cell values (nearest upsample -> plain half-res fetch)
        int rd = ((d + g - 1) >> 1) + 1;    // kd == g for tl in [0,9)
#pragma unroll
        for (int vi = 0; vi < 4; vi++) {
            int v = wave * 4 + vi;
            int w = w0 + v;
            unsigned short* sb = smem + v * SST + lane;
#pragma unroll
            for (int tl = 0; tl < 9; tl++) {
                int kh2 = tl / 3, kw2 = tl % 3;
                int rh = ((h + kh2 - 1) >> 1) + 1;
                int rw = ((w + kw2 - 1) >> 1) + 1;
                int cell = (rd * 18 + rh) * 18 + rw;
                sb[tl * 64] = f2bf(xt[cell * 64 + lane]);
            }
        }
        __syncthreads();
        // MFMA: 9 K-steps x 3 M-tiles
#pragma unroll
        for (int s = 0; s < 9; s++) {
            int k_local = kh * 288 + s * 32;
            int kb = ((g * 576 + k_local) >> 3) + quad;
            short8 bfrag = *(const short8*)(smem + col * SST + k_local + quad * 8);
            short8 a0 = wo8[kb * 96 + mh * 48 + col];
            short8 a1 = wo8[kb * 96 + mh * 48 + 16 + col];
            short8 a2 = wo8[kb * 96 + mh * 48 + 32 + col];
            oacc0 = __builtin_amdgcn_mfma_f32_16x16x32_bf16(a0, bfrag, oacc0, 0, 0, 0);
            oacc1 = __builtin_amdgcn_mfma_f32_16x16x32_bf16(a1, bfrag, oacc1, 0, 0, 0);
            oacc2 = __builtin_amdgcn_mfma_f32_16x16x32_bf16(a2, bfrag, oacc2, 0, 0, 0);
        }
    }
    __syncthreads();
    if (kh == 1) {
#pragma unroll
        for (int r = 0; r < 4; r++) {
            Pl[(mh * 48 +      quad * 4 + r) * 16 + col] = oacc0[r];
            Pl[(mh * 48 + 16 + quad * 4 + r) * 16 + col] = oacc1[r];
            Pl[(mh * 48 + 32 + quad * 4 + r) * 16 + col] = oacc2[r];
        }
    }
    __syncthreads();
    if (kh == 0) {
#pragma unroll
        for (int r = 0; r < 4; r++) {
            int m0 = mh * 48 + quad * 4 + r;
            Pl[m0 * 16 + col] = oacc0[r] + Pl[m0 * 16 + col] + b_off[m0];
            int m1 = m0 + 16;
            Pl[m1 * 16 + col] = oacc1[r] + Pl[m1 * 16 + col] + b_off[m1];
            int m2 = m0 + 32;
            if (m2 < 81)
                Pl[m2 * 16 + col] = oacc2[r] + Pl[m2 * 16 + col] + b_off[m2];
        }
    }
    // Pl now holds off_l[kc][v] for kc<81 (sync at top of phase-1 loop)

    // ================= Phase 1: deform sample + GEMM =================
    int mt = wave & 1;                      // kh reused as K-half
    floatx4 acc = {0.f, 0.f, 0.f, 0.f};
    const short8* wa8 = (const short8*)wa;

#pragma unroll 1
    for (int g = 0; g < 3; g++) {
        __syncthreads();   // off_l ready (g=0) / prior gather+MFMA reads done
        if (tid < 144) {
            int v = tid & 15, tl = tid >> 4;
            int tap = g * 9 + tl;
            int kh2 = tl / 3, kw2 = tl % 3;
            int w = w0 + v;
            float od = Pl[(3 * tap + 0) * 16 + v];
            float oh = Pl[(3 * tap + 1) * 16 + v];
            float ow = Pl[(3 * tap + 2) * 16 + v];
            float pdc = (float)(d + g - 1) + od;
            float phc = (float)(h + kh2 - 1) + oh;
            float pwc = (float)(w + kw2 - 1) + ow;
            float fd0 = floorf(pdc), fh0 = floorf(phc), fw0 = floorf(pwc);
            float fd = pdc - fd0, fh = phc - fh0, fw = pwc - fw0;
            int id = (int)fd0, ih = (int)fh0, iw = (int)fw0;
            int rd0 = ((min(max(id,     -2), 33) >> 1) + 1) * (324 * 64);
            int rd1 = ((min(max(id + 1, -2), 33) >> 1) + 1) * (324 * 64);
            int rh0 = ((min(max(ih,     -2), 33) >> 1) + 1) * (18 * 64);
            int rh1 = ((min(max(ih + 1, -2), 33) >> 1) + 1) * (18 * 64);
            int rw0 = ((min(max(iw,     -2), 33) >> 1) + 1) * 64;
            int rw1 = ((min(max(iw + 1, -2), 33) >> 1) + 1) * 64;
            int* A = cba + tid * 8;
            float* W = cbw + tid * 8;
            A[0] = rd0 + rh0 + rw0; A[1] = rd0 + rh0 + rw1;
            A[2] = rd0 + rh1 + rw0; A[3] = rd0 + rh1 + rw1;
            A[4] = rd1 + rh0 + rw0; A[5] = rd1 + rh0 + rw1;
            A[6] = rd1 + rh1 + rw0; A[7] = rd1 + rh1 + rw1;
            float gd = 1.f - fd, gh = 1.f - fh, gw = 1.f - fw;
            W[0] = gd * gh * gw; W[1] = gd * gh * fw;
            W[2] = gd * fh * gw; W[3] = gd * fh * fw;
            W[4] = fd * gh * gw; W[5] = fd * gh * fw;
            W[6] = fd * fh * gw; W[7] = fd * fh * fw;
        }
        __syncthreads();

        // Gather: S[v][tl*64 + lane] (bf16, conflict-free LDS writes)
#pragma unroll
        for (int vi = 0; vi < 4; vi++) {
            int v = wave * 4 + vi;
            unsigned short* sb = smem + v * SST + lane;
#pragma unroll
            for (int tl = 0; tl < 9; tl++) {
                int item = tl * 16 + v;
                const int4*   a4 = (const int4*)(cba + item * 8);
                const float4* w4 = (const float4*)(cbw + item * 8);
                int4 a0 = a4[0], a1 = a4[1];
                float4 wv0 = w4[0], wv1 = w4[1];
                float s = wv0.x * xt[a0.x + lane] + wv0.y * xt[a0.y + lane]
                        + wv0.z * xt[a0.z + lane] + wv0.w * xt[a0.w + lane]
                        + wv1.x * xt[a1.x + lane] + wv1.y * xt[a1.y + lane]
                        + wv1.z * xt[a1.z + lane] + wv1.w * xt[a1.w + lane];
                sb[tl * 64] = f2bf(s);
            }
        }
        __syncthreads();

        // MFMA over this K-chunk (576), split across kh halves
#pragma unroll
        for (int s = 0; s < 9; s++) {
            int k_local = kh * 288 + s * 32;
            int kb = ((g * 576 + k_local) >> 3) + quad;
            short8 afrag = wa8[kb * 32 + mt * 16 + col];
            short8 bfrag = *(const short8*)(smem + col * SST + k_local + quad * 8);
            acc = __builtin_amdgcn_mfma_f32_16x16x32_bf16(afrag, bfrag, acc, 0, 0, 0);
        }
    }
    __syncthreads();        // off_l dead; Pl reusable as pbuf

    if (kh == 1) {
#pragma unroll
        for (int r = 0; r < 4; r++) Pl[mt * 256 + (quad * 4 + r) * 16 + col] = acc[r];
    }
    __syncthreads();
    if (kh == 0) {
#pragma unroll
        for (int r = 0; r < 4; r++) {
            int o = mt * 16 + quad * 4 + r;
            float val = acc[r] + Pl[mt * 256 + (quad * 4 + r) * 16 + col] + bias[o];
            out[o * NVOX + pbase + col] = val;
            atomicAdd(&rsum[o], val);
            atomicAdd(&rsq[o], val * val);
        }
    }
    __syncthreads();
    if (tid < COUT) {
        atomicAdd(&gstat[tid], rsum[tid]);
        atomicAdd(&gstat[COUT + tid], rsq[tid]);
    }
}

// ---------------------------------------------------------------------------
// BN finalize + ReLU, in-place on d_out.
// ---------------------------------------------------------------------------
__global__ void bn_kernel(const float* __restrict__ ws,
                          const float* __restrict__ gamma,
                          const float* __restrict__ beta,
                          float* out) {
    int i = blockIdx.x * 256 + threadIdx.x;
    int o = i >> 15;
    const float* gstat = ws + WS_STAT;
    const float inv = 1.f / 32768.f;
    float mean = gstat[o] * inv;
    float var  = gstat[COUT + o] * inv - mean * mean;
    float sc   = rsqrtf(var + 1e-5f) * gamma[o];
    float v = (out[i] - mean) * sc + beta[o];
    out[i] = fmaxf(v, 0.f);
}

// ---------------------------------------------------------------------------
extern "C" void kernel_launch(void* const* d_in, const int* in_sizes, int n_in,
                              void* d_out, int out_size, void* d_ws, size_t ws_size,
                              hipStream_t stream) {
    const float* x     = (const float*)d_in[0];
    const float* w_off = (const float*)d_in[1];
    const float* b_off = (const float*)d_in[2];
    const float* wmat  = (const float*)d_in[3];
    const float* bias  = (const float*)d_in[4];
    const float* gamma = (const float*)d_in[5];
    const float* beta  = (const float*)d_in[6];
    float* ws  = (float*)d_ws;
    float* out = (float*)d_out;

    prep_all_kernel<<<5941, 64, 0, stream>>>(x, w_off, wmat, ws);
    deform_kernel<<<2048, 256, 0, stream>>>(b_off, bias, ws, out);
    bn_kernel<<<4096, 256, 0, stream>>>(ws, gamma, beta, out);
}